// Round 9
// baseline (276.582 us; speedup 1.0000x reference)
//
#include <hip/hip_runtime.h>
#include <stdint.h>

#define BATCH 64
#define CDIM  64
#define NPTS  1024
#define ODIM  128
#define KNN   49
#define KNNP  52      // padded knn row stride (16B-aligned: 52*4=208=16*13)
#define BNEPS 1e-5f

typedef __attribute__((ext_vector_type(8))) short bf16x8;   // 8 bf16 (4 VGPRs)
typedef __attribute__((ext_vector_type(4))) float f32x4;

__device__ __forceinline__ int mbcnt64(unsigned long long m) {
    return __builtin_amdgcn_mbcnt_hi((uint32_t)(m >> 32),
           __builtin_amdgcn_mbcnt_lo((uint32_t)m, 0));
}

// ---- workspace layout (bytes) ----
#define O_XF   0
#define SZ_XF  (BATCH*64*2*64*8*4)        // 16,777,216  bf16 hi/lo fragments
#define O_SQ   (O_XF + SZ_XF)
#define SZ_SQ  (BATCH*NPTS*4)             // 262,144    per-col squared norms
#define O_KNN  (O_SQ + SZ_SQ)
#define SZ_KNN (BATCH*NPTS*KNNP*4)        // 13,631,488 knn indices (padded)
#define WS_NEED ((size_t)(O_KNN + SZ_KNN))

// out[b*O+o] = beta - gamma*mean*rsqrt(var+eps)   (fallback path init)
__global__ void gcn_init(const float* __restrict__ gamma, const float* __restrict__ beta,
                         const float* __restrict__ rmean, const float* __restrict__ rvar,
                         float* __restrict__ out) {
    int i = blockIdx.x * 256 + threadIdx.x;
    if (i < BATCH * ODIM) {
        int o = i & (ODIM - 1);
        out[i] = beta[o] - gamma[o] * rmean[o] * rsqrtf(rvar[o] + BNEPS);
    }
}

// ======================= K0: bf16 hi/lo split + MFMA-fragment swizzle + sq ==============
// First 32 blocks also write the BN-constant init of out (folds gcn_init's launch).
__global__ __launch_bounds__(256) void k0_split(const float* __restrict__ X,
                                                uint32_t* __restrict__ XF,
                                                float* __restrict__ sq,
                                                const float* __restrict__ gamma,
                                                const float* __restrict__ beta,
                                                const float* __restrict__ rmean,
                                                const float* __restrict__ rvar,
                                                float* __restrict__ out) {
    if (blockIdx.x < 32) {                           // 32*256 = 8192 = BATCH*ODIM
        int i = blockIdx.x * 256 + threadIdx.x;
        int o = i & (ODIM - 1);
        out[i] = beta[o] - gamma[o] * rmean[o] * rsqrtf(rvar[o] + BNEPS);
    }
    const int b    = blockIdx.x >> 4;
    const int t16  = (blockIdx.x & 15) * 4 + (threadIdx.x >> 6);
    const int lane = threadIdx.x & 63;
    const int n    = t16 * 16 + (lane & 15);
    const int cg   = lane >> 4;
    const float* Xb = X + (size_t)b * CDIM * NPTS;
    float s = 0.f;
    for (int ks = 0; ks < 2; ks++) {
        uint32_t hi[4], lo[4];
#pragma unroll
        for (int dj = 0; dj < 4; dj++) {
            uint32_t hw[2], lw[2];
#pragma unroll
            for (int e = 0; e < 2; e++) {
                int c = ks * 32 + cg * 8 + dj * 2 + e;
                float x = Xb[(size_t)c * NPTS + n];
                s += x * x;
                uint32_t u  = __float_as_uint(x);
                uint32_t hr = (u + 0x7FFFu + ((u >> 16) & 1u)) >> 16;   // RTNE bf16
                float    hf = __uint_as_float(hr << 16);
                uint32_t ul = __float_as_uint(x - hf);
                uint32_t lr = (ul + 0x7FFFu + ((ul >> 16) & 1u)) >> 16;
                hw[e] = hr; lw[e] = lr;
            }
            hi[dj] = hw[0] | (hw[1] << 16);
            lo[dj] = lw[0] | (lw[1] << 16);
        }
        size_t entry = ((size_t)(b * 64 + t16) * 2 + ks) * 64 + lane;
        uint32_t* p = XF + entry * 8;
        *(uint4*)p       = make_uint4(hi[0], hi[1], hi[2], hi[3]);
        *(uint4*)(p + 4) = make_uint4(lo[0], lo[1], lo[2], lo[3]);
    }
    s += __shfl_xor(s, 16, 64);
    s += __shfl_xor(s, 32, 64);
    if (lane < 16) sq[b * NPTS + n] = s;
}

// ======================= K1: MFMA Gram + 16-bit select (32 rows, 4-row ILP) =============
// 512 threads (8 waves), 32 rows/block: each B fragment feeds 12 MFMA (2 A-sets),
// halving per-row staging vs the 16-row shell. Keys = top-16 bits of the monotone
// map, packed 2 rows/uint (64 KB LDS). Select: wave w owns rows 4w..4w+3 -- 4
// interleaved ballot binary searches over [wave_min, max_of_lane_mins]. Emit:
// ballot+mbcnt into a reused LDS region, then block-wide coalesced int4 write-back
// (kills the 4x RMW write amplification seen in round 8).
__global__ __launch_bounds__(512) void k1_gram_select(const uint32_t* __restrict__ XF,
                                                      const float* __restrict__ sq,
                                                      int* __restrict__ knn) {
    __shared__ uint32_t s_pk[16 * 1024];             // 64 KB packed keys; emit reuse
    const int b    = blockIdx.x >> 5;
    const int rt   = blockIdx.x & 31;                // 32-row tile
    const int wave = threadIdx.x >> 6, lane = threadIdx.x & 63;
    const int q = lane >> 4, l15 = lane & 15;

    // A fragments for both 16-row sets (rows rt*32 .. rt*32+31)
    bf16x8 ahi[2][2], alo[2][2];
#pragma unroll
    for (int s = 0; s < 2; s++)
#pragma unroll
        for (int ks = 0; ks < 2; ks++) {
            const uint32_t* p = XF + (size_t)((b * 64 + rt * 2 + s) * 2 + ks) * 512 + lane * 8;
            ahi[s][ks] = *(const bf16x8*)p;
            alo[s][ks] = *(const bf16x8*)(p + 4);
        }
    const float* sqb = sq + b * NPTS;

#pragma unroll
    for (int tt = 0; tt < 8; tt++) {                 // wave's 8 col-tiles
        const int t16 = wave * 8 + tt;
        const uint32_t* pB = XF + (size_t)((b * 64 + t16) * 2) * 512 + lane * 8;
        bf16x8 bhi0 = *(const bf16x8*)pB;
        bf16x8 blo0 = *(const bf16x8*)(pB + 4);
        bf16x8 bhi1 = *(const bf16x8*)(pB + 512);
        bf16x8 blo1 = *(const bf16x8*)(pB + 516);
        const int col  = t16 * 16 + l15;
        const float sqv = sqb[col];
#pragma unroll
        for (int s = 0; s < 2; s++) {                // both A-sets reuse B fragments
            f32x4 acc = {0.f, 0.f, 0.f, 0.f};
            acc = __builtin_amdgcn_mfma_f32_16x16x32_bf16(ahi[s][0], bhi0, acc, 0, 0, 0);
            acc = __builtin_amdgcn_mfma_f32_16x16x32_bf16(alo[s][0], bhi0, acc, 0, 0, 0);
            acc = __builtin_amdgcn_mfma_f32_16x16x32_bf16(ahi[s][0], blo0, acc, 0, 0, 0);
            acc = __builtin_amdgcn_mfma_f32_16x16x32_bf16(ahi[s][1], bhi1, acc, 0, 0, 0);
            acc = __builtin_amdgcn_mfma_f32_16x16x32_bf16(alo[s][1], bhi1, acc, 0, 0, 0);
            acc = __builtin_amdgcn_mfma_f32_16x16x32_bf16(ahi[s][1], blo1, acc, 0, 0, 0);
            float d[4];
#pragma unroll
            for (int i = 0; i < 4; i++)              // C layout: row=(lane>>4)*4+reg
                d[i] = fmaf(-2.f, acc[i], sqv);      // sq_r dropped (row-monotone)
            if (t16 == rt * 2 + s) {                 // wave-uniform diag tile: self=inf
#pragma unroll
                for (int i = 0; i < 4; i++)
                    if (l15 == q * 4 + i) d[i] = __uint_as_float(0x7F800000u);
            }
            uint32_t key[4];
#pragma unroll
            for (int i = 0; i < 4; i++) {
                uint32_t u = __float_as_uint(d[i]);
                key[i] = ((int)u < 0) ? ~u : (u | 0x80000000u);
            }
            // pack high halves: low16 = key[0]>>16, high16 = key[1]>>16
            uint32_t pk01 = __builtin_amdgcn_perm(key[1], key[0], 0x07060302);
            uint32_t pk23 = __builtin_amdgcn_perm(key[3], key[2], 0x07060302);
            const int p0 = s * 8 + 2 * q, p1 = p0 + 1;   // pair p holds rows 2p,2p+1
            s_pk[p0 * 1024 + (col ^ ((p0 & 3) << 3))] = pk01;
            s_pk[p1 * 1024 + (col ^ ((p1 & 3) << 3))] = pk23;
        }
    }
    __syncthreads();

    // ---- load this wave's 4 rows of keys (local rows 4w..4w+3 = pairs 2w,2w+1) ----
    uint32_t k[4][16];
    {
        const int p0 = 2 * wave, p1 = 2 * wave + 1;
        const int sw0 = (p0 & 3) << 3, sw1 = (p1 & 3) << 3;
#pragma unroll
        for (int tt = 0; tt < 16; tt++) {
            uint32_t a  = s_pk[p0 * 1024 + ((tt * 64 + lane) ^ sw0)];
            uint32_t bb = s_pk[p1 * 1024 + ((tt * 64 + lane) ^ sw1)];
            k[0][tt] = a & 0xFFFFu;  k[1][tt] = a >> 16;
            k[2][tt] = bb & 0xFFFFu; k[3][tt] = bb >> 16;
        }
    }
    __syncthreads();                                 // s_pk now dead -> emit staging

    // ---- bounds per row: lo = wave min, hi = max over lanes of lane-min ----
    uint32_t lo[4], hi[4];
    {
#pragma unroll
        for (int r = 0; r < 4; r++) {
            uint32_t m = k[r][0];
#pragma unroll
            for (int tt = 1; tt < 16; tt++) m = k[r][tt] < m ? k[r][tt] : m;
            lo[r] = m; hi[r] = m;
        }
#pragma unroll
        for (int off = 1; off < 64; off <<= 1) {
#pragma unroll
            for (int r = 0; r < 4; r++) {
                uint32_t a = (uint32_t)__shfl_xor((int)lo[r], off, 64);
                uint32_t m = (uint32_t)__shfl_xor((int)hi[r], off, 64);
                lo[r] = a < lo[r] ? a : lo[r];
                hi[r] = m > hi[r] ? m : hi[r];       // cnt(<=hi) >= 64 >= KNN
            }
        }
    }

    // ---- 4 interleaved exact binary searches (16-bit space, ~6-9 iters) ----
    for (int it = 0; it < 16; it++) {
        bool a0 = lo[0] < hi[0], a1 = lo[1] < hi[1];
        bool a2 = lo[2] < hi[2], a3 = lo[3] < hi[3];
        if (!a0 && !a1 && !a2 && !a3) break;
        uint32_t mid[4];
        int cnt[4] = {0, 0, 0, 0};
#pragma unroll
        for (int r = 0; r < 4; r++) mid[r] = (lo[r] + hi[r]) >> 1;
#pragma unroll
        for (int tt = 0; tt < 16; tt++) {
            cnt[0] += __popcll(__ballot(k[0][tt] <= mid[0]));
            cnt[1] += __popcll(__ballot(k[1][tt] <= mid[1]));
            cnt[2] += __popcll(__ballot(k[2][tt] <= mid[2]));
            cnt[3] += __popcll(__ballot(k[3][tt] <= mid[3]));
        }
#pragma unroll
        for (int r = 0; r < 4; r++)
            if (lo[r] < hi[r]) {
                if (cnt[r] >= KNN) hi[r] = mid[r]; else lo[r] = mid[r] + 1;
            }
    }

    // ---- emit into LDS staging (s_pk reused), then coalesced write-back ----
    int* eknn = (int*)s_pk;                          // [32][KNNP] = 6656 B
#pragma unroll
    for (int r = 0; r < 4; r++) {
        const int lrow = 4 * wave + r;
        const uint32_t vstar = lo[r];
        int total_lt = 0;
#pragma unroll
        for (int tt = 0; tt < 16; tt++)
            total_lt += __popcll(__ballot(k[r][tt] < vstar));
        int base_lt = 0, base_eq = total_lt;         // total_lt <= 48 by minimality
#pragma unroll
        for (int tt = 0; tt < 16; tt++) {
            bool islt = k[r][tt] < vstar;
            bool iseq = k[r][tt] == vstar;
            unsigned long long mlt = __ballot(islt);
            unsigned long long meq = __ballot(iseq);
            if (mlt | meq) {                         // wave-uniform skip of empty tiles
                int pos = islt ? (base_lt + mbcnt64(mlt)) : (base_eq + mbcnt64(meq));
                if (islt || (iseq && pos < KNN)) eknn[lrow * KNNP + pos] = tt * 64 + lane;
            }
            base_lt += __popcll(mlt);
            base_eq += __popcll(meq);
        }
    }
    __syncthreads();
    {                                                // 32*KNNP ints = 416 int4, contiguous
        const int t = threadIdx.x;
        int* kbase = knn + ((size_t)b * NPTS + rt * 32) * KNNP;
        if (t < 416) *(int4*)&kbase[t * 4] = *(const int4*)&eknn[t * 4];
    }
}

// ======================= K2: fused gather + GEMM + relu/BN/pool =========================
// 512 blocks = (b, nq of 128 rows), 256 threads. thread = (row rl, 4ch-group gg).
// 8 channel-slices: stage XT8 (8ch x 1024, 32 KB), each thread gathers its row's 49
// neighbors for its 4ch -> z kept in registers (32 floats). After the loop the XT8
// region is reused as the 128x64 z-tile; k2b-style GEMM + pooled BN epilogue follows.
__global__ __launch_bounds__(256) void k2_fused(const float* __restrict__ X,
                                                const int* __restrict__ knn,
                                                const float* __restrict__ W,
                                                const float* __restrict__ bias,
                                                const float* __restrict__ gamma,
                                                const float* __restrict__ rvar,
                                                float* __restrict__ out) {
    __shared__ __align__(16) float XT8[8 * 1024];    // 32 KB; reused as z-tile
    __shared__ float s_red[256];
    const int b = blockIdx.x >> 3, nq = blockIdx.x & 7;
    const int t = threadIdx.x;
    const int rl = t >> 1, gg = t & 1;
    const int row = nq * 128 + rl;
    const int* kr = knn + ((size_t)b * NPTS + row) * KNNP;
    int4 j[13];
#pragma unroll
    for (int c = 0; c < 13; c++) j[c] = *(const int4*)&kr[c * 4];   // 49 valid (+3 pad)

    float4 zacc[8];
    for (int cg8 = 0; cg8 < 8; cg8++) {
        __syncthreads();                             // prev slice's readers done
        const float* Xc = X + ((size_t)b * CDIM + cg8 * 8) * NPTS;
#pragma unroll
        for (int k4 = 0; k4 < 4; k4++) {             // stage 8ch x 1024 transposed
            int n = k4 * 256 + t;
#pragma unroll
            for (int g2 = 0; g2 < 2; g2++) {
                float4 v;
                v.x = Xc[(size_t)(g2 * 4 + 0) * NPTS + n];
                v.y = Xc[(size_t)(g2 * 4 + 1) * NPTS + n];
                v.z = Xc[(size_t)(g2 * 4 + 2) * NPTS + n];
                v.w = Xc[(size_t)(g2 * 4 + 3) * NPTS + n];
                int sl = (g2 ^ (n & 1)) << 2;
                *(float4*)&XT8[n * 8 + sl] = v;
            }
        }
        __syncthreads();
        float4 s = {0.f, 0.f, 0.f, 0.f};
#pragma unroll
        for (int c = 0; c < 12; c++) {               // 48 neighbors
            int js[4] = {j[c].x, j[c].y, j[c].z, j[c].w};
#pragma unroll
            for (int e = 0; e < 4; e++) {
                int jj = js[e];
                float4 v = *(const float4*)&XT8[jj * 8 + ((gg ^ (jj & 1)) << 2)];
                s.x += v.x; s.y += v.y; s.z += v.z; s.w += v.w;
            }
        }
        {                                            // neighbor 48
            int jj = j[12].x;
            float4 v = *(const float4*)&XT8[jj * 8 + ((gg ^ (jj & 1)) << 2)];
            s.x += v.x; s.y += v.y; s.z += v.z; s.w += v.w;
        }
        zacc[cg8] = s;
    }
    __syncthreads();
    float* ZT = XT8;                                 // reuse as z-tile [128][64] rotated
#pragma unroll
    for (int cg8 = 0; cg8 < 8; cg8++) {
        int colr = ((cg8 * 8 + gg * 4) + (rl & 15) * 4) & 63;
        *(float4*)&ZT[rl * 64 + colr] = zacc[cg8];
    }
    __syncthreads();

    // ---- GEMM: thread = (o, row-half h); W rows in registers; z via LDS broadcast ----
    const int o = t & 127, h = t >> 7;
    float4 wv[16];
#pragma unroll
    for (int c4 = 0; c4 < 16; c4++)
        wv[c4] = *(const float4*)&W[(size_t)o * CDIM + c4 * 4];
    const float bo = bias[o];
    float rsum = 0.f;
    for (int r = 0; r < 64; r++) {
        const int zr = h * 64 + r;
        const float* zrow = &ZT[zr * 64];
        const int rot = (zr & 15) * 4;
        float a = 0.f;
#pragma unroll
        for (int c4 = 0; c4 < 16; c4++) {
            float4 zv = *(const float4*)&zrow[(c4 * 4 + rot) & 63];  // wave-uniform
            a += wv[c4].x * zv.x + wv[c4].y * zv.y + wv[c4].z * zv.z + wv[c4].w * zv.w;
        }
        rsum += fmaxf(a * (1.f / KNN) + bo, 0.f);
    }
    s_red[t] = rsum;
    __syncthreads();
    if (t < 128) {
        float sum = s_red[t] + s_red[t + 128];
        float scale = gamma[t] * rsqrtf(rvar[t] + BNEPS) * (1.f / NPTS);
        atomicAdd(&out[b * ODIM + t], sum * scale);
    }
}

// ======================= Fallback: round-1 fused kernel (no workspace) ==================
#define RTILE 8
#define APAD  1028
#define WPAD  132
#define POOLF (64 * WPAD)

__global__ __launch_bounds__(256) void gcn_main(
    const float* __restrict__ X, const float* __restrict__ W,
    const float* __restrict__ bias, const float* __restrict__ gamma,
    const float* __restrict__ rvar, float* __restrict__ out)
{
    __shared__ __align__(16) float s_pool[POOLF];
    __shared__ __align__(16) float s_fstage[4][APAD];
    __shared__ int   s_knn[RTILE][KNN];
    __shared__ float s_z[RTILE][CDIM];

    const int t = threadIdx.x;
    const int b = blockIdx.x >> 7;
    const int rtile = blockIdx.x & 127;
    const int r0 = rtile * RTILE;
    const float* Xb = X + (size_t)b * CDIM * NPTS;

    float acc[RTILE][4];
    float sqv[4];
#pragma unroll
    for (int r = 0; r < RTILE; r++)
#pragma unroll
        for (int u = 0; u < 4; u++) acc[r][u] = 0.f;
#pragma unroll
    for (int u = 0; u < 4; u++) sqv[u] = 0.f;

    for (int ch = 0; ch < 16; ch++) {
        const int c0 = ch * 4;
#pragma unroll
        for (int cc = 0; cc < 4; cc++) {
            float4 v = *(const float4*)(Xb + (size_t)(c0 + cc) * NPTS + 4 * t);
            *(float4*)&s_fstage[cc][4 * t] = v;
        }
        __syncthreads();
#pragma unroll
        for (int cc = 0; cc < 4; cc++) {
            float4 bv4 = *(const float4*)&s_fstage[cc][4 * t];
            float bv[4] = {bv4.x, bv4.y, bv4.z, bv4.w};
#pragma unroll
            for (int u = 0; u < 4; u++) sqv[u] += bv[u] * bv[u];
            const float* arow = Xb + (size_t)(c0 + cc) * NPTS + r0;
            float4 a0 = *(const float4*)(arow);
            float4 a1 = *(const float4*)(arow + 4);
            float av[8] = {a0.x, a0.y, a0.z, a0.w, a1.x, a1.y, a1.z, a1.w};
#pragma unroll
            for (int r = 0; r < RTILE; r++)
#pragma unroll
                for (int u = 0; u < 4; u++) acc[r][u] += av[r] * bv[u];
        }
        __syncthreads();
    }

    float* s_dist = s_pool;
#pragma unroll
    for (int r = 0; r < RTILE; r++) {
        const int rG = r0 + r;
        float d[4];
#pragma unroll
        for (int u = 0; u < 4; u++) {
            float dd = sqv[u] - 2.f * acc[r][u];
            d[u] = (4 * t + u == rG) ? __uint_as_float(0x7F800000u) : dd;
        }
        *(float4*)&s_dist[r * NPTS + 4 * t] = make_float4(d[0], d[1], d[2], d[3]);
    }
    __syncthreads();

    const int wave = t >> 6, lane = t & 63;
    const unsigned long long ltmask = (1ull << lane) - 1ull;
    for (int rr = 0; rr < 2; rr++) {
        const int row = wave * 2 + rr;
        unsigned key[16];
#pragma unroll
        for (int tt = 0; tt < 16; tt++) {
            unsigned u = __float_as_uint(s_dist[row * NPTS + tt * 64 + lane]);
            key[tt] = (u & 0x80000000u) ? ~u : (u | 0x80000000u);
        }
        unsigned lo = 0u, hi = 0xFFFFFFFFu;
        while (lo < hi) {
            unsigned mid = lo + ((hi - lo) >> 1);
            int cnt = 0;
#pragma unroll
            for (int tt = 0; tt < 16; tt++)
                cnt += __popcll(__ballot(key[tt] <= mid));
            if (cnt >= KNN) hi = mid; else lo = mid + 1;
        }
        const unsigned v49 = lo;
        int cntless = 0;
#pragma unroll
        for (int tt = 0; tt < 16; tt++)
            cntless += __popcll(__ballot(key[tt] < v49));
        const int need = KNN - cntless;
        int base = 0, eqtaken = 0;
#pragma unroll
        for (int tt = 0; tt < 16; tt++) {
            bool islt = key[tt] < v49;
            bool iseq = key[tt] == v49;
            unsigned long long meq = __ballot(iseq);
            int eqrank = eqtaken + __popcll(meq & ltmask);
            bool sel = islt || (iseq && (eqrank < need));
            unsigned long long msel = __ballot(sel);
            if (sel) {
                int pos = base + __popcll(msel & ltmask);
                s_knn[row][pos] = tt * 64 + lane;
            }
            base    += __popcll(msel);
            eqtaken += __popcll(meq);
        }
    }
    __syncthreads();

    float* astage = s_pool;
    float* s_redf = (float*)s_fstage;
    const int ar = t >> 5, acc8 = (t & 31) >> 2, ks = t & 3;
    for (int c0 = 0; c0 < CDIM; c0 += 8) {
#pragma unroll
        for (int qq = 0; qq < 8; qq++) {
            int if4 = qq * 256 + t;
            int cc = if4 >> 8, j4 = if4 & 255;
            float4 v = *(const float4*)(Xb + (size_t)(c0 + cc) * NPTS + 4 * j4);
            *(float4*)&astage[cc * APAD + 4 * j4] = v;
        }
        __syncthreads();
        float partial = 0.f;
        for (int k = ks; k < KNN; k += 4)
            partial += astage[acc8 * APAD + s_knn[ar][k]];
        s_redf[t] = partial;
        __syncthreads();
        if (t < 64) {
            int r = t >> 3, cc = t & 7;
            int bi = r * 32 + cc * 4;
            s_z[r][c0 + cc] = s_redf[bi] + s_redf[bi + 1] + s_redf[bi + 2] + s_redf[bi + 3];
        }
        __syncthreads();
    }

    float* wt = s_pool;
#pragma unroll 4
    for (int qq = 0; qq < 32; qq++) {
        int e = qq * 256 + t;
        int o = e >> 6, c = e & 63;
        wt[c * WPAD + o] = W[e];
    }
    __syncthreads();
    const int o = t & 127, rg = t >> 7;
    float facc[4] = {0.f, 0.f, 0.f, 0.f};
    for (int c = 0; c < CDIM; c += 4) {
        float w0 = wt[(c + 0) * WPAD + o], w1 = wt[(c + 1) * WPAD + o];
        float w2 = wt[(c + 2) * WPAD + o], w3 = wt[(c + 3) * WPAD + o];
#pragma unroll
        for (int qq = 0; qq < 4; qq++) {
            float4 zv = *(const float4*)&s_z[rg * 4 + qq][c];
            facc[qq] += w0 * zv.x + w1 * zv.y + w2 * zv.z + w3 * zv.w;
        }
    }
    const float bo = bias[o];
    float rsum = 0.f;
#pragma unroll
    for (int qq = 0; qq < 4; qq++) {
        float f = facc[qq] * (1.f / KNN) + bo;
        rsum += fmaxf(f, 0.f);
    }
    s_redf[t] = rsum;
    __syncthreads();
    if (t < 128) {
        float scale = gamma[t] * rsqrtf(rvar[t] + BNEPS) * (1.f / NPTS);
        atomicAdd(&out[b * ODIM + t], (s_redf[t] + s_redf[t + 128]) * scale);
    }
}

extern "C" void kernel_launch(void* const* d_in, const int* in_sizes, int n_in,
                              void* d_out, int out_size, void* d_ws, size_t ws_size,
                              hipStream_t stream) {
    const float* X     = (const float*)d_in[0];
    const float* W     = (const float*)d_in[1];
    const float* bias  = (const float*)d_in[2];
    const float* gamma = (const float*)d_in[3];
    const float* beta  = (const float*)d_in[4];
    const float* rmean = (const float*)d_in[5];
    const float* rvar  = (const float*)d_in[6];
    float* out = (float*)d_out;

    if (ws_size >= WS_NEED) {
        uint8_t* ws = (uint8_t*)d_ws;
        uint32_t* XF  = (uint32_t*)(ws + O_XF);
        float*    sqw = (float*)(ws + O_SQ);
        int*      knn = (int*)(ws + O_KNN);
        k0_split<<<BATCH * 16, 256, 0, stream>>>(X, XF, sqw, gamma, beta, rmean, rvar, out);
        k1_gram_select<<<BATCH * 32, 512, 0, stream>>>(XF, sqw, knn);
        k2_fused<<<BATCH * 8, 256, 0, stream>>>(X, knn, W, bias, gamma, rvar, out);
    } else {
        gcn_init<<<(BATCH * ODIM + 255) / 256, 256, 0, stream>>>(gamma, beta, rmean, rvar, out);
        gcn_main<<<BATCH * (NPTS / RTILE), 256, 0, stream>>>(X, W, bias, gamma, rvar, out);
    }
}